// Round 1
// baseline (279.450 us; speedup 1.0000x reference)
//
#include <hip/hip_runtime.h>

#define BB 2
#define SS 2048
#define PP 2048
#define TT 4096
#define EE 1024
#define HH 16
#define DH 64

typedef __attribute__((ext_vector_type(8))) __bf16 bf16x8;
typedef __attribute__((ext_vector_type(4))) __bf16 bf16x4;
typedef __attribute__((ext_vector_type(4))) float f32x4;

__device__ __forceinline__ void gload_lds16(const void* g, void* l) {
  __builtin_amdgcn_global_load_lds(
      (const __attribute__((address_space(1))) void*)g,
      (__attribute__((address_space(3))) void*)l, 16, 0, 0);
}

#define MFMA16(a, b, c) __builtin_amdgcn_mfma_f32_16x16x32_bf16((a), (b), (c), 0, 0, 0)

// ---------------- fp32 -> bf16 conversion (8 arrays, grid.y selects) ----------------
struct ConvDesc {
  const float* s[8];
  __bf16* d[8];
  int n4[8];
};

__global__ __launch_bounds__(256) void convert_f32_bf16(ConvDesc cd) {
  const int a = blockIdx.y;
  const float* __restrict__ src = cd.s[a];
  __bf16* __restrict__ dst = cd.d[a];
  const int n4 = cd.n4[a];
  const int stride = gridDim.x * blockDim.x;
  for (int i = blockIdx.x * blockDim.x + threadIdx.x; i < n4; i += stride) {
    float4 v = ((const float4*)src)[i];
    bf16x4 o = {(__bf16)v.x, (__bf16)v.y, (__bf16)v.z, (__bf16)v.w};
    ((bf16x4*)dst)[i] = o;
  }
}

// ---------------- past_v [B,H,P,DH] f32  ->  Vt [B,H,DH,T] bf16 (cols 0..P) ----------------
__global__ __launch_bounds__(256) void transpose_pastv(const float* __restrict__ pv,
                                                       __bf16* __restrict__ vt) {
  __shared__ float tile[64][65];
  const int bh = blockIdx.y;
  const int k0 = blockIdx.x * 64;
  const int tx = threadIdx.x & 63, ty = threadIdx.x >> 6;
#pragma unroll
  for (int i = 0; i < 16; ++i) {
    const int r = ty + i * 4;
    tile[r][tx] = pv[((size_t)bh * PP + k0 + r) * DH + tx];
  }
  __syncthreads();
#pragma unroll
  for (int i = 0; i < 16; ++i) {
    const int d = ty + i * 4;
    vt[((size_t)bh * DH + d) * TT + k0 + tx] = (__bf16)tile[tx][d];
  }
}

// ---------------- shared 128x128x(K=1024) bf16 GEMM core (C = A * Bt^T) ----------------
__device__ __forceinline__ void gemm_core(const __bf16* A, const __bf16* Bt, __bf16* As,
                                          __bf16* Bs, int m0, int n0, f32x4 acc[4][4]) {
  const int tid = threadIdx.x, w = tid >> 6, lane = tid & 63;
  const int l15 = lane & 15, lg = lane >> 4;
  const int wr = w >> 1, wc = w & 1;
  const int cidx = w * 128 + lane;
  const int r0 = cidx >> 2, c0 = cidx & 3;   // row 0..127, 16B chunk 0..3
  const int r1 = r0 + 16;
  for (int kt = 0; kt < 32; ++kt) {
    const int k0 = kt * 32;
    if (kt) __syncthreads();
    gload_lds16(A + (size_t)(m0 + r0) * EE + k0 + c0 * 8, As + w * 1024);
    gload_lds16(A + (size_t)(m0 + r1) * EE + k0 + c0 * 8, As + w * 1024 + 512);
    gload_lds16(Bt + (size_t)(n0 + r0) * EE + k0 + c0 * 8, Bs + w * 1024);
    gload_lds16(Bt + (size_t)(n0 + r1) * EE + k0 + c0 * 8, Bs + w * 1024 + 512);
    __syncthreads();
    bf16x8 af[4], bf[4];
#pragma unroll
    for (int mi = 0; mi < 4; ++mi)
      af[mi] = *(const bf16x8*)&As[(wr * 64 + mi * 16 + l15) * 32 + lg * 8];
#pragma unroll
    for (int ni = 0; ni < 4; ++ni)
      bf[ni] = *(const bf16x8*)&Bs[(wc * 64 + ni * 16 + l15) * 32 + lg * 8];
#pragma unroll
    for (int mi = 0; mi < 4; ++mi)
#pragma unroll
      for (int ni = 0; ni < 4; ++ni) acc[mi][ni] = MFMA16(af[mi], bf[ni], acc[mi][ni]);
  }
}

// ---------------- QKV projections (z = 0:Q(scaled) 1:K 2:V(transposed into Vt)) ----------------
__global__ __launch_bounds__(256) void proj_qkv(
    const __bf16* __restrict__ xq, const __bf16* __restrict__ xk, const __bf16* __restrict__ xv,
    const __bf16* __restrict__ wqb, const __bf16* __restrict__ wkb, const __bf16* __restrict__ wvb,
    __bf16* __restrict__ qws, __bf16* __restrict__ kproj, __bf16* __restrict__ vt) {
  __shared__ alignas(16) __bf16 As[4096];
  __shared__ alignas(16) __bf16 Bs[4096];
  const int z = blockIdx.z;
  const __bf16* A = (z == 0) ? xq : (z == 1) ? xk : xv;
  const __bf16* Bt = (z == 0) ? wqb : (z == 1) ? wkb : wvb;
  const int m0 = blockIdx.y * 128, n0 = blockIdx.x * 128;
  f32x4 acc[4][4];
  const f32x4 fz = {0.f, 0.f, 0.f, 0.f};
#pragma unroll
  for (int mi = 0; mi < 4; ++mi)
#pragma unroll
    for (int ni = 0; ni < 4; ++ni) acc[mi][ni] = fz;
  gemm_core(A, Bt, As, Bs, m0, n0, acc);

  const int tid = threadIdx.x, w = tid >> 6, lane = tid & 63;
  const int l15 = lane & 15, lg = lane >> 4;
  const int wr = w >> 1, wc = w & 1;
  if (z < 2) {
    __bf16* dst = (z == 0) ? qws : kproj;
    const float sc = (z == 0) ? 0.125f : 1.0f;  // fold 1/sqrt(DH) into Q
#pragma unroll
    for (int mi = 0; mi < 4; ++mi)
#pragma unroll
      for (int ni = 0; ni < 4; ++ni) {
        const int mb = m0 + wr * 64 + mi * 16 + lg * 4;
        const int n = n0 + wc * 64 + ni * 16 + l15;
#pragma unroll
        for (int r = 0; r < 4; ++r)
          dst[(size_t)(mb + r) * EE + n] = (__bf16)(acc[mi][ni][r] * sc);
      }
  } else {
#pragma unroll
    for (int mi = 0; mi < 4; ++mi)
#pragma unroll
      for (int ni = 0; ni < 4; ++ni) {
        const int mb = m0 + wr * 64 + mi * 16 + lg * 4;
        const int n = n0 + wc * 64 + ni * 16 + l15;
        const int bb = mb >> 11, s = mb & (SS - 1);
        const int hh = n >> 6, dd = n & 63;
        bf16x4 pk = {(__bf16)acc[mi][ni][0], (__bf16)acc[mi][ni][1], (__bf16)acc[mi][ni][2],
                     (__bf16)acc[mi][ni][3]};
        *(bf16x4*)&vt[((size_t)(bb * HH + hh) * DH + dd) * TT + PP + s] = pk;
      }
  }
}

// ---------------- output projection: attn_out @ Wo^T -> fp32 d_out ----------------
__global__ __launch_bounds__(256) void gemm_out(const __bf16* __restrict__ A,
                                                const __bf16* __restrict__ Bt,
                                                float* __restrict__ C) {
  __shared__ alignas(16) __bf16 As[4096];
  __shared__ alignas(16) __bf16 Bs[4096];
  const int m0 = blockIdx.y * 128, n0 = blockIdx.x * 128;
  f32x4 acc[4][4];
  const f32x4 fz = {0.f, 0.f, 0.f, 0.f};
#pragma unroll
  for (int mi = 0; mi < 4; ++mi)
#pragma unroll
    for (int ni = 0; ni < 4; ++ni) acc[mi][ni] = fz;
  gemm_core(A, Bt, As, Bs, m0, n0, acc);

  const int tid = threadIdx.x, w = tid >> 6, lane = tid & 63;
  const int l15 = lane & 15, lg = lane >> 4;
  const int wr = w >> 1, wc = w & 1;
#pragma unroll
  for (int mi = 0; mi < 4; ++mi)
#pragma unroll
    for (int ni = 0; ni < 4; ++ni) {
      const int mb = m0 + wr * 64 + mi * 16 + lg * 4;
      const int n = n0 + wc * 64 + ni * 16 + l15;
#pragma unroll
      for (int r = 0; r < 4; ++r) C[(size_t)(mb + r) * EE + n] = acc[mi][ni][r];
    }
}

// ---------------- flash attention: QBLK=128 (8 waves x 16 rows), KVBLK=64 ----------------
__global__ __launch_bounds__(512) void attn_kernel(const __bf16* __restrict__ q_ws,
                                                   const __bf16* __restrict__ kpast,
                                                   const __bf16* __restrict__ kproj,
                                                   const __bf16* __restrict__ vt,
                                                   __bf16* __restrict__ attn_out) {
  __shared__ alignas(16) __bf16 Kls[4096];       // [64 keys][64 d], chunk-swizzled
  __shared__ alignas(16) __bf16 Vls[4096];       // [64 d][64 keys], chunk-swizzled
  __shared__ alignas(16) __bf16 Pls[8 * 1024];   // per-wave [16 q][64 keys], swizzled

  const int tid = threadIdx.x;
  const int wv = tid >> 6;
  const int lane = tid & 63;
  const int l15 = lane & 15, lg = lane >> 4;

  const int qb = blockIdx.x;  // 0..15
  const int bh = blockIdx.y;  // 0..31
  const int b = bh >> 4, h = bh & 15;
  const int i0 = qb * 128;

  // Q fragments (pre-scaled by 0.125 at projection)
  const size_t qoff = ((size_t)(b * SS + i0 + wv * 16 + l15)) * EE + h * DH + lg * 8;
  const bf16x8 qf0 = *(const bf16x8*)(q_ws + qoff);
  const bf16x8 qf1 = *(const bf16x8*)(q_ws + qoff + 32);

  f32x4 o[4];
  float mrow[4], lrow[4];
  const f32x4 fz = {0.f, 0.f, 0.f, 0.f};
#pragma unroll
  for (int dt = 0; dt < 4; ++dt) o[dt] = fz;
#pragma unroll
  for (int r = 0; r < 4; ++r) {
    mrow[r] = -1e30f;
    lrow[r] = 0.f;
  }

  // staging: thread -> (row, chunk); source chunk pre-swizzled so linear LDS is XOR-swizzled
  const int srow = tid >> 3;                  // 0..63
  const int cg = (tid & 7) ^ (srow & 7);      // swizzled global 16B chunk
  __bf16* kdst = &Kls[wv * 512];
  __bf16* vdst = &Vls[wv * 512];
  const __bf16* vgbase = vt + ((size_t)bh * DH + srow) * TT + cg * 8;
  __bf16* pb = &Pls[wv * 1024];

  const int ntiles = 2 * qb + 34;  // last visible key = i0+127+PP
  for (int t = 0; t < ntiles; ++t) {
    const int kv0 = t * 64;
    __syncthreads();  // previous iteration's LDS reads complete
    const __bf16* kg;
    if (t < 32)
      kg = kpast + ((size_t)bh * PP + kv0 + srow) * DH + cg * 8;
    else
      kg = kproj + ((size_t)(b * SS + (kv0 - PP) + srow)) * EE + h * DH + cg * 8;
    gload_lds16(kg, kdst);
    gload_lds16(vgbase + kv0, vdst);
    __syncthreads();  // drains vmcnt -> tiles ready

    // ---- QK^T: scores [16 q][64 keys] per wave ----
    f32x4 sc[4];
#pragma unroll
    for (int kt = 0; kt < 4; ++kt) sc[kt] = fz;
#pragma unroll
    for (int kt = 0; kt < 4; ++kt) {
      const int krow = kt * 16 + l15;
      const int swz = krow & 7;
      const bf16x8 kf0 = *(const bf16x8*)&Kls[krow * 64 + ((lg ^ swz) << 3)];
      const bf16x8 kf1 = *(const bf16x8*)&Kls[krow * 64 + (((4 + lg) ^ swz) << 3)];
      sc[kt] = MFMA16(qf0, kf0, sc[kt]);
      sc[kt] = MFMA16(qf1, kf1, sc[kt]);
    }

    // ---- causal mask (only last two tiles can be partial) ----
    if (kv0 + 63 > i0 + PP) {
#pragma unroll
      for (int kt = 0; kt < 4; ++kt)
#pragma unroll
        for (int r = 0; r < 4; ++r) {
          const int j = kv0 + kt * 16 + l15;
          const int i = i0 + wv * 16 + lg * 4 + r;
          if (j > i + PP) sc[kt][r] = -1e30f;
        }
    }

    // ---- online softmax (rows live in 16-lane groups) ----
    float rmax[4];
#pragma unroll
    for (int r = 0; r < 4; ++r)
      rmax[r] = fmaxf(fmaxf(sc[0][r], sc[1][r]), fmaxf(sc[2][r], sc[3][r]));
#pragma unroll
    for (int msk = 1; msk < 16; msk <<= 1)
#pragma unroll
      for (int r = 0; r < 4; ++r) rmax[r] = fmaxf(rmax[r], __shfl_xor(rmax[r], msk, 64));
#pragma unroll
    for (int r = 0; r < 4; ++r) {
      const float mnew = fmaxf(mrow[r], rmax[r]);
      const float alpha = __builtin_amdgcn_exp2f((mrow[r] - mnew) * 1.44269504f);
      mrow[r] = mnew;
      lrow[r] *= alpha;
#pragma unroll
      for (int dt = 0; dt < 4; ++dt) o[dt][r] *= alpha;
    }
    float rsum[4] = {0.f, 0.f, 0.f, 0.f};
#pragma unroll
    for (int kt = 0; kt < 4; ++kt)
#pragma unroll
      for (int r = 0; r < 4; ++r) {
        const float p = __builtin_amdgcn_exp2f((sc[kt][r] - mrow[r]) * 1.44269504f);
        sc[kt][r] = p;
        rsum[r] += p;
      }
#pragma unroll
    for (int msk = 1; msk < 16; msk <<= 1)
#pragma unroll
      for (int r = 0; r < 4; ++r) rsum[r] += __shfl_xor(rsum[r], msk, 64);
#pragma unroll
    for (int r = 0; r < 4; ++r) lrow[r] += rsum[r];

    // ---- P -> LDS (C-frag layout -> A-frag layout), swizzled ----
#pragma unroll
    for (int kt = 0; kt < 4; ++kt)
#pragma unroll
      for (int r = 0; r < 4; ++r) {
        const int prow = lg * 4 + r;
        const int key = kt * 16 + l15;
        pb[prow * 64 + ((((key >> 3) ^ (prow & 7)) << 3) | (key & 7))] = (__bf16)sc[kt][r];
      }
    __syncthreads();

    // ---- PV: O += P[16x64] * V[64x64] ----
#pragma unroll
    for (int kc = 0; kc < 2; ++kc) {
      const int pswz = l15 & 7;
      const bf16x8 pf = *(const bf16x8*)&pb[l15 * 64 + (((kc * 4 + lg) ^ pswz) << 3)];
#pragma unroll
      for (int dt = 0; dt < 4; ++dt) {
        const int vrow = dt * 16 + l15;
        const bf16x8 vf = *(const bf16x8*)&Vls[vrow * 64 + (((kc * 4 + lg) ^ (vrow & 7)) << 3)];
        o[dt] = MFMA16(pf, vf, o[dt]);
      }
    }
  }

  // ---- epilogue: normalize, write [B,S,E] bf16 ----
#pragma unroll
  for (int r = 0; r < 4; ++r) {
    const float inv = 1.0f / lrow[r];
    const size_t row = (size_t)b * SS + i0 + wv * 16 + lg * 4 + r;
#pragma unroll
    for (int dt = 0; dt < 4; ++dt)
      attn_out[row * EE + h * DH + dt * 16 + l15] = (__bf16)(o[dt][r] * inv);
  }
}

// ---------------- launch ----------------
extern "C" void kernel_launch(void* const* d_in, const int* in_sizes, int n_in, void* d_out,
                              int out_size, void* d_ws, size_t ws_size, hipStream_t stream) {
  const float* query = (const float*)d_in[0];
  const float* key_in = (const float*)d_in[1];
  const float* value = (const float*)d_in[2];
  const float* past_k = (const float*)d_in[3];
  const float* past_v = (const float*)d_in[4];
  // d_in[5] = attn_mask: analytic causal, not loaded
  const float* Wq = (const float*)d_in[6];
  const float* Wk = (const float*)d_in[7];
  const float* Wv = (const float*)d_in[8];
  const float* Wo = (const float*)d_in[9];

  char* ws = (char*)d_ws;
  __bf16* XQ = (__bf16*)(ws + 0);                  // [4096,1024]
  __bf16* XK = (__bf16*)(ws + 8388608);
  __bf16* XV = (__bf16*)(ws + 16777216);
  __bf16* WQB = (__bf16*)(ws + 25165824);          // [1024,1024] x4
  __bf16* WKB = (__bf16*)(ws + 27262976);
  __bf16* WVB = (__bf16*)(ws + 29360128);
  __bf16* WOB = (__bf16*)(ws + 31457280);
  __bf16* QW = (__bf16*)(ws + 33554432);           // Q, [B,S,E], pre-scaled
  __bf16* KP = (__bf16*)(ws + 41943040);           // past_k bf16 [B,H,P,DH]
  __bf16* KN = (__bf16*)(ws + 50331648);           // new K [B,S,E]
  __bf16* VT = (__bf16*)(ws + 58720256);           // V^T [B,H,DH,T]
  __bf16* AO = (__bf16*)(ws + 75497472);           // attn out [B,S,E]

  ConvDesc cd;
  cd.s[0] = query;  cd.d[0] = XQ;  cd.n4[0] = 1048576;
  cd.s[1] = key_in; cd.d[1] = XK;  cd.n4[1] = 1048576;
  cd.s[2] = value;  cd.d[2] = XV;  cd.n4[2] = 1048576;
  cd.s[3] = Wq;     cd.d[3] = WQB; cd.n4[3] = 262144;
  cd.s[4] = Wk;     cd.d[4] = WKB; cd.n4[4] = 262144;
  cd.s[5] = Wv;     cd.d[5] = WVB; cd.n4[5] = 262144;
  cd.s[6] = Wo;     cd.d[6] = WOB; cd.n4[6] = 262144;
  cd.s[7] = past_k; cd.d[7] = KP;  cd.n4[7] = 1048576;

  convert_f32_bf16<<<dim3(1024, 8, 1), 256, 0, stream>>>(cd);
  transpose_pastv<<<dim3(32, 32, 1), 256, 0, stream>>>(past_v, VT);
  proj_qkv<<<dim3(8, 32, 3), 256, 0, stream>>>(XQ, XK, XV, WQB, WKB, WVB, QW, KN, VT);
  attn_kernel<<<dim3(16, 32, 1), 512, 0, stream>>>(QW, KP, KN, VT, AO);
  gemm_out<<<dim3(8, 32, 1), 256, 0, stream>>>(AO, WOB, (float*)d_out);
}

// Round 2
// 212.358 us; speedup vs baseline: 1.3159x; 1.3159x over previous
//
#include <hip/hip_runtime.h>

#define BB 2
#define SS 2048
#define PP 2048
#define TT 4096
#define EE 1024
#define HH 16
#define DH 64

typedef __attribute__((ext_vector_type(8))) __bf16 bf16x8;
typedef __attribute__((ext_vector_type(4))) __bf16 bf16x4;
typedef __attribute__((ext_vector_type(4))) float f32x4;
typedef __attribute__((ext_vector_type(16))) float f32x16;

__device__ __forceinline__ void gload_lds16(const void* g, void* l) {
  __builtin_amdgcn_global_load_lds(
      (const __attribute__((address_space(1))) void*)g,
      (__attribute__((address_space(3))) void*)l, 16, 0, 0);
}

#define MFMA16(a, b, c) __builtin_amdgcn_mfma_f32_16x16x32_bf16((a), (b), (c), 0, 0, 0)
#define MFMA32(a, b, c) __builtin_amdgcn_mfma_f32_32x32x16_bf16((a), (b), (c), 0, 0, 0)

__device__ __forceinline__ unsigned cvtpk_bf16(float lo, float hi) {
  unsigned r;
  asm("v_cvt_pk_bf16_f32 %0, %1, %2" : "=v"(r) : "v"(lo), "v"(hi));
  return r;
}

// ---------------- fp32 -> bf16 conversion (8 arrays, grid.y selects) ----------------
struct ConvDesc {
  const float* s[8];
  __bf16* d[8];
  int n4[8];
};

__global__ __launch_bounds__(256) void convert_f32_bf16(ConvDesc cd) {
  const int a = blockIdx.y;
  const float* __restrict__ src = cd.s[a];
  __bf16* __restrict__ dst = cd.d[a];
  const int n4 = cd.n4[a];
  const int stride = gridDim.x * blockDim.x;
  for (int i = blockIdx.x * blockDim.x + threadIdx.x; i < n4; i += stride) {
    float4 v = ((const float4*)src)[i];
    bf16x4 o = {(__bf16)v.x, (__bf16)v.y, (__bf16)v.z, (__bf16)v.w};
    ((bf16x4*)dst)[i] = o;
  }
}

// ---------------- past_v [B,H,P,DH] f32  ->  Vt [B,H,DH,T] bf16 (cols 0..P) ----------------
__global__ __launch_bounds__(256) void transpose_pastv(const float* __restrict__ pv,
                                                       __bf16* __restrict__ vt) {
  __shared__ float tile[64][65];
  const int bh = blockIdx.y;
  const int k0 = blockIdx.x * 64;
  const int tx = threadIdx.x & 63, ty = threadIdx.x >> 6;
#pragma unroll
  for (int i = 0; i < 16; ++i) {
    const int r = ty + i * 4;
    tile[r][tx] = pv[((size_t)bh * PP + k0 + r) * DH + tx];
  }
  __syncthreads();
#pragma unroll
  for (int i = 0; i < 16; ++i) {
    const int d = ty + i * 4;
    vt[((size_t)bh * DH + d) * TT + k0 + tx] = (__bf16)tile[tx][d];
  }
}

// ---------------- shared 128x128x(K=1024) bf16 GEMM core (C = A * Bt^T) ----------------
__device__ __forceinline__ void gemm_core(const __bf16* A, const __bf16* Bt, __bf16* As,
                                          __bf16* Bs, int m0, int n0, f32x4 acc[4][4]) {
  const int tid = threadIdx.x, w = tid >> 6, lane = tid & 63;
  const int l15 = lane & 15, lg = lane >> 4;
  const int wr = w >> 1, wc = w & 1;
  const int cidx = w * 128 + lane;
  const int r0 = cidx >> 2, c0 = cidx & 3;   // row 0..127, 16B chunk 0..3
  const int r1 = r0 + 16;
  for (int kt = 0; kt < 32; ++kt) {
    const int k0 = kt * 32;
    if (kt) __syncthreads();
    gload_lds16(A + (size_t)(m0 + r0) * EE + k0 + c0 * 8, As + w * 1024);
    gload_lds16(A + (size_t)(m0 + r1) * EE + k0 + c0 * 8, As + w * 1024 + 512);
    gload_lds16(Bt + (size_t)(n0 + r0) * EE + k0 + c0 * 8, Bs + w * 1024);
    gload_lds16(Bt + (size_t)(n0 + r1) * EE + k0 + c0 * 8, Bs + w * 1024 + 512);
    __syncthreads();
    bf16x8 af[4], bf[4];
#pragma unroll
    for (int mi = 0; mi < 4; ++mi)
      af[mi] = *(const bf16x8*)&As[(wr * 64 + mi * 16 + l15) * 32 + lg * 8];
#pragma unroll
    for (int ni = 0; ni < 4; ++ni)
      bf[ni] = *(const bf16x8*)&Bs[(wc * 64 + ni * 16 + l15) * 32 + lg * 8];
#pragma unroll
    for (int mi = 0; mi < 4; ++mi)
#pragma unroll
      for (int ni = 0; ni < 4; ++ni) acc[mi][ni] = MFMA16(af[mi], bf[ni], acc[mi][ni]);
  }
}

// ---------------- QKV projections (z = 0:Q(scaled) 1:K 2:V(transposed into Vt)) ----------------
__global__ __launch_bounds__(256) void proj_qkv(
    const __bf16* __restrict__ xq, const __bf16* __restrict__ xk, const __bf16* __restrict__ xv,
    const __bf16* __restrict__ wqb, const __bf16* __restrict__ wkb, const __bf16* __restrict__ wvb,
    __bf16* __restrict__ qws, __bf16* __restrict__ kproj, __bf16* __restrict__ vt) {
  __shared__ alignas(16) __bf16 As[4096];
  __shared__ alignas(16) __bf16 Bs[4096];
  const int z = blockIdx.z;
  const __bf16* A = (z == 0) ? xq : (z == 1) ? xk : xv;
  const __bf16* Bt = (z == 0) ? wqb : (z == 1) ? wkb : wvb;
  const int m0 = blockIdx.y * 128, n0 = blockIdx.x * 128;
  f32x4 acc[4][4];
  const f32x4 fz = {0.f, 0.f, 0.f, 0.f};
#pragma unroll
  for (int mi = 0; mi < 4; ++mi)
#pragma unroll
    for (int ni = 0; ni < 4; ++ni) acc[mi][ni] = fz;
  gemm_core(A, Bt, As, Bs, m0, n0, acc);

  const int tid = threadIdx.x, w = tid >> 6, lane = tid & 63;
  const int l15 = lane & 15, lg = lane >> 4;
  const int wr = w >> 1, wc = w & 1;
  if (z < 2) {
    __bf16* dst = (z == 0) ? qws : kproj;
    const float sc = (z == 0) ? 0.125f : 1.0f;  // fold 1/sqrt(DH) into Q
#pragma unroll
    for (int mi = 0; mi < 4; ++mi)
#pragma unroll
      for (int ni = 0; ni < 4; ++ni) {
        const int mb = m0 + wr * 64 + mi * 16 + lg * 4;
        const int n = n0 + wc * 64 + ni * 16 + l15;
#pragma unroll
        for (int r = 0; r < 4; ++r)
          dst[(size_t)(mb + r) * EE + n] = (__bf16)(acc[mi][ni][r] * sc);
      }
  } else {
#pragma unroll
    for (int mi = 0; mi < 4; ++mi)
#pragma unroll
      for (int ni = 0; ni < 4; ++ni) {
        const int mb = m0 + wr * 64 + mi * 16 + lg * 4;
        const int n = n0 + wc * 64 + ni * 16 + l15;
        const int bb = mb >> 11, s = mb & (SS - 1);
        const int hh = n >> 6, dd = n & 63;
        bf16x4 pk = {(__bf16)acc[mi][ni][0], (__bf16)acc[mi][ni][1], (__bf16)acc[mi][ni][2],
                     (__bf16)acc[mi][ni][3]};
        *(bf16x4*)&vt[((size_t)(bb * HH + hh) * DH + dd) * TT + PP + s] = pk;
      }
  }
}

// ---------------- output projection: attn_out @ Wo^T -> fp32 d_out ----------------
__global__ __launch_bounds__(256) void gemm_out(const __bf16* __restrict__ A,
                                                const __bf16* __restrict__ Bt,
                                                float* __restrict__ C) {
  __shared__ alignas(16) __bf16 As[4096];
  __shared__ alignas(16) __bf16 Bs[4096];
  const int m0 = blockIdx.y * 128, n0 = blockIdx.x * 128;
  f32x4 acc[4][4];
  const f32x4 fz = {0.f, 0.f, 0.f, 0.f};
#pragma unroll
  for (int mi = 0; mi < 4; ++mi)
#pragma unroll
    for (int ni = 0; ni < 4; ++ni) acc[mi][ni] = fz;
  gemm_core(A, Bt, As, Bs, m0, n0, acc);

  const int tid = threadIdx.x, w = tid >> 6, lane = tid & 63;
  const int l15 = lane & 15, lg = lane >> 4;
  const int wr = w >> 1, wc = w & 1;
#pragma unroll
  for (int mi = 0; mi < 4; ++mi)
#pragma unroll
    for (int ni = 0; ni < 4; ++ni) {
      const int mb = m0 + wr * 64 + mi * 16 + lg * 4;
      const int n = n0 + wc * 64 + ni * 16 + l15;
#pragma unroll
      for (int r = 0; r < 4; ++r) C[(size_t)(mb + r) * EE + n] = acc[mi][ni][r];
    }
}

// ---------------- flash attention v2: 4 waves x 32 q-rows, KVBLK=64, 32x32 MFMA ----------------
// Swapped QK^T (S^T = K*Q^T) puts softmax row lane-local (q = lane&31).
// PV as O^T = V^T * P^T keeps O column lane-local -> lane-scalar rescale.
// P f32 -> bf16 B-frags in-register via v_cvt_pk_bf16_f32 + v_permlane32_swap_b32.
// K/V double-buffered in LDS, counted vmcnt(4) + raw barriers (2 barriers/tile).
__global__ __launch_bounds__(256) void attn_kernel(const __bf16* __restrict__ q_ws,
                                                   const __bf16* __restrict__ kpast,
                                                   const __bf16* __restrict__ kproj,
                                                   const __bf16* __restrict__ vt,
                                                   __bf16* __restrict__ attn_out) {
  __shared__ alignas(16) __bf16 lds[2][2][4096];  // [buf][K/V][64 rows x 64 cols], XOR-swizzled

  const int tid = threadIdx.x;
  const int w = tid >> 6, lane = tid & 63;
  const int l31 = lane & 31, hi = lane >> 5, l7 = lane & 7;

  const int qb = blockIdx.x;  // 0..15
  const int bh = blockIdx.y;  // 0..31
  const int b = bh >> 4, h = bh & 15;
  const int i0 = qb * 128;
  const int qw0 = i0 + w * 32;  // wave's first q row

  // ---- Q B-frags: lane holds Q[q=qw0+l31][k=16c+hi*8+j], pre-scaled by 0.125 ----
  bf16x8 qf[4];
  {
    const __bf16* qbase = q_ws + (size_t)(b * SS + qw0 + l31) * EE + h * DH + hi * 8;
#pragma unroll
    for (int c = 0; c < 4; ++c) qf[c] = *(const bf16x8*)(qbase + 16 * c);
  }

  // ---- accumulators: O^T C-frags, col=q=lane&31, row=d=(r&3)+8*(r>>2)+4*hi+32*dblk ----
  f32x16 oacc[2];
#pragma unroll
  for (int dblk = 0; dblk < 2; ++dblk)
#pragma unroll
    for (int r = 0; r < 16; ++r) oacc[dblk][r] = 0.f;
  float m_run = -1e30f, l_run = 0.f;

  // ---- staging map: slot = i*256 + w*64 + lane -> row = slot>>3, lin chunk = lane&7 ----
  // LDS[row][cl] holds global chunk cg = cl ^ (row&7)  (row&7 == (lane>>3)&7)
  const int sr = (lane >> 3);              // + i*32 + w*8
  const int scg = (lane & 7) ^ (sr & 7);   // pre-swizzled global chunk

#define STAGE(buf, t)                                                                        \
  {                                                                                          \
    const int kv0_ = (t)*64;                                                                 \
    _Pragma("unroll") for (int i = 0; i < 2; ++i) {                                          \
      const int row_ = i * 32 + w * 8 + sr;                                                  \
      const __bf16* kg_ =                                                                    \
          ((t) < 32) ? kpast + ((size_t)bh * PP + kv0_ + row_) * DH + scg * 8                \
                     : kproj + ((size_t)(b * SS + kv0_ - PP + row_)) * EE + h * DH + scg * 8; \
      gload_lds16(kg_, &lds[buf][0][i * 2048 + w * 512]);                                    \
    }                                                                                        \
    _Pragma("unroll") for (int i = 0; i < 2; ++i) {                                          \
      const int row_ = i * 32 + w * 8 + sr;                                                  \
      gload_lds16(vt + ((size_t)bh * DH + row_) * TT + kv0_ + scg * 8,                       \
                  &lds[buf][1][i * 2048 + w * 512]);                                         \
    }                                                                                        \
  }

  const int ntiles = 2 * qb + 34;  // last visible key = i0+127+PP
  STAGE(0, 0);

  for (int t = 0; t < ntiles; ++t) {
    const int cur = t & 1;
    if (t + 1 < ntiles) {
      STAGE(cur ^ 1, t + 1);
      asm volatile("s_waitcnt vmcnt(4)" ::: "memory");  // tile t staged; t+1 stays in flight
    } else {
      asm volatile("s_waitcnt vmcnt(0)" ::: "memory");
    }
    __builtin_amdgcn_s_barrier();

    const int kv0 = t * 64;
    if (kv0 <= qw0 + 31 + PP) {  // wave-uniform: tile at least partially visible
      // ---- QK^T: S^T[key][q], 2 key-subtiles x 4 d-chunks ----
      f32x16 p[2];
#pragma unroll
      for (int s = 0; s < 2; ++s)
#pragma unroll
        for (int r = 0; r < 16; ++r) p[s][r] = 0.f;
      const __bf16* Kb = lds[cur][0];
#pragma unroll
      for (int s = 0; s < 2; ++s)
#pragma unroll
        for (int c = 0; c < 4; ++c) {
          const bf16x8 kf = *(const bf16x8*)&Kb[(32 * s + l31) * 64 + (((2 * c + hi) ^ l7) << 3)];
          p[s] = MFMA32(kf, qf[c], p[s]);
        }

      // ---- causal mask (boundary tiles only) ----
      if (kv0 + 63 > qw0 + PP) {
        const int qa = qw0 + l31 + PP;
#pragma unroll
        for (int s = 0; s < 2; ++s)
#pragma unroll
          for (int r = 0; r < 16; ++r) {
            const int key = kv0 + 32 * s + (r & 3) + 8 * (r >> 2) + 4 * hi;
            if (key > qa) p[s][r] = -1e30f;
          }
      }

      // ---- online softmax: row q is lane-local; lane^32 holds the other 32 keys ----
      float q16[16];
#pragma unroll
      for (int r = 0; r < 16; ++r) q16[r] = fmaxf(p[0][r], p[1][r]);
#pragma unroll
      for (int st = 8; st > 0; st >>= 1)
#pragma unroll
        for (int r = 0; r < st; ++r) q16[r] = fmaxf(q16[r], q16[r + st]);
      float rmax = fmaxf(q16[0], __shfl_xor(q16[0], 32, 64));

      const float mnew = fmaxf(m_run, rmax);
      const float alpha = __builtin_amdgcn_exp2f((m_run - mnew) * 1.44269504f);
      const float mb = mnew * 1.44269504f;
      m_run = mnew;

#pragma unroll
      for (int s = 0; s < 2; ++s)
#pragma unroll
        for (int r = 0; r < 16; ++r)
          p[s][r] = __builtin_amdgcn_exp2f(__builtin_fmaf(p[s][r], 1.44269504f, -mb));
      float s16[16];
#pragma unroll
      for (int r = 0; r < 16; ++r) s16[r] = p[0][r] + p[1][r];
#pragma unroll
      for (int st = 8; st > 0; st >>= 1)
#pragma unroll
        for (int r = 0; r < st; ++r) s16[r] += s16[r + st];
      const float rsum = s16[0] + __shfl_xor(s16[0], 32, 64);
      l_run = l_run * alpha + rsum;
#pragma unroll
      for (int dblk = 0; dblk < 2; ++dblk)
#pragma unroll
        for (int r = 0; r < 16; ++r) oacc[dblk][r] *= alpha;

      // ---- P(f32) -> P^T B-frags (bf16) via cvt_pk + permlane32_swap ----
      bf16x8 pb[4];
#pragma unroll
      for (int s = 0; s < 2; ++s)
#pragma unroll
        for (int u = 0; u < 2; ++u) {
          unsigned a0 = cvtpk_bf16(p[s][8 * u + 0], p[s][8 * u + 1]);
          unsigned a1 = cvtpk_bf16(p[s][8 * u + 2], p[s][8 * u + 3]);
          unsigned b0 = cvtpk_bf16(p[s][8 * u + 4], p[s][8 * u + 5]);
          unsigned b1 = cvtpk_bf16(p[s][8 * u + 6], p[s][8 * u + 7]);
          asm volatile("v_permlane32_swap_b32 %0, %1" : "+v"(a0), "+v"(b0));
          asm volatile("v_permlane32_swap_b32 %0, %1" : "+v"(a1), "+v"(b1));
          union {
            unsigned u32[4];
            bf16x8 v;
          } pk;
          pk.u32[0] = a0;  // keys 16m + {0,1} / {8,9}
          pk.u32[1] = a1;  // keys 16m + {2,3} / {10,11}
          pk.u32[2] = b0;  // keys 16m + {4,5} / {12,13}
          pk.u32[3] = b1;  // keys 16m + {6,7} / {14,15}
          pb[2 * s + u] = pk.v;
        }

      // ---- PV: O^T += V^T * P^T, 2 d-blocks x 4 key-chunks ----
      const __bf16* Vb = lds[cur][1];
#pragma unroll
      for (int dblk = 0; dblk < 2; ++dblk)
#pragma unroll
        for (int u = 0; u < 4; ++u) {
          const bf16x8 vf =
              *(const bf16x8*)&Vb[(32 * dblk + l31) * 64 + (((2 * u + hi) ^ l7) << 3)];
          oacc[dblk] = MFMA32(vf, pb[u], oacc[dblk]);
        }
    }
    __builtin_amdgcn_s_barrier();  // all reads of buf[cur] done before it is restaged
  }

  // ---- epilogue: normalize (lane-local l), write [B,S,E] bf16 ----
  const float inv = 1.0f / l_run;
  const size_t orow = (size_t)(b * SS + qw0 + l31) * EE + h * DH;
#pragma unroll
  for (int dblk = 0; dblk < 2; ++dblk)
#pragma unroll
    for (int g = 0; g < 4; ++g) {
      bf16x4 v4;
#pragma unroll
      for (int r4 = 0; r4 < 4; ++r4) v4[r4] = (__bf16)(oacc[dblk][4 * g + r4] * inv);
      *(bf16x4*)&attn_out[orow + 32 * dblk + 8 * g + 4 * hi] = v4;
    }
}

// ---------------- launch ----------------
extern "C" void kernel_launch(void* const* d_in, const int* in_sizes, int n_in, void* d_out,
                              int out_size, void* d_ws, size_t ws_size, hipStream_t stream) {
  const float* query = (const float*)d_in[0];
  const float* key_in = (const float*)d_in[1];
  const float* value = (const float*)d_in[2];
  const float* past_k = (const float*)d_in[3];
  const float* past_v = (const float*)d_in[4];
  // d_in[5] = attn_mask: analytic causal, not loaded
  const float* Wq = (const float*)d_in[6];
  const float* Wk = (const float*)d_in[7];
  const float* Wv = (const float*)d_in[8];
  const float* Wo = (const float*)d_in[9];

  char* ws = (char*)d_ws;
  __bf16* XQ = (__bf16*)(ws + 0);                  // [4096,1024]
  __bf16* XK = (__bf16*)(ws + 8388608);
  __bf16* XV = (__bf16*)(ws + 16777216);
  __bf16* WQB = (__bf16*)(ws + 25165824);          // [1024,1024] x4
  __bf16* WKB = (__bf16*)(ws + 27262976);
  __bf16* WVB = (__bf16*)(ws + 29360128);
  __bf16* WOB = (__bf16*)(ws + 31457280);
  __bf16* QW = (__bf16*)(ws + 33554432);           // Q, [B,S,E], pre-scaled
  __bf16* KP = (__bf16*)(ws + 41943040);           // past_k bf16 [B,H,P,DH]
  __bf16* KN = (__bf16*)(ws + 50331648);           // new K [B,S,E]
  __bf16* VT = (__bf16*)(ws + 58720256);           // V^T [B,H,DH,T]
  __bf16* AO = (__bf16*)(ws + 75497472);           // attn out [B,S,E]

  ConvDesc cd;
  cd.s[0] = query;  cd.d[0] = XQ;  cd.n4[0] = 1048576;
  cd.s[1] = key_in; cd.d[1] = XK;  cd.n4[1] = 1048576;
  cd.s[2] = value;  cd.d[2] = XV;  cd.n4[2] = 1048576;
  cd.s[3] = Wq;     cd.d[3] = WQB; cd.n4[3] = 262144;
  cd.s[4] = Wk;     cd.d[4] = WKB; cd.n4[4] = 262144;
  cd.s[5] = Wv;     cd.d[5] = WVB; cd.n4[5] = 262144;
  cd.s[6] = Wo;     cd.d[6] = WOB; cd.n4[6] = 262144;
  cd.s[7] = past_k; cd.d[7] = KP;  cd.n4[7] = 1048576;

  convert_f32_bf16<<<dim3(1024, 8, 1), 256, 0, stream>>>(cd);
  transpose_pastv<<<dim3(32, 32, 1), 256, 0, stream>>>(past_v, VT);
  proj_qkv<<<dim3(8, 32, 3), 256, 0, stream>>>(XQ, XK, XV, WQB, WKB, WVB, QW, KN, VT);
  attn_kernel<<<dim3(16, 32, 1), 256, 0, stream>>>(QW, KP, KN, VT, AO);
  gemm_out<<<dim3(8, 32, 1), 256, 0, stream>>>(AO, WOB, (float*)d_out);
}

// Round 3
// 207.304 us; speedup vs baseline: 1.3480x; 1.0244x over previous
//
#include <hip/hip_runtime.h>

#define BB 2
#define SS 2048
#define PP 2048
#define TT 4096
#define EE 1024
#define HH 16
#define DH 64

typedef __attribute__((ext_vector_type(8))) __bf16 bf16x8;
typedef __attribute__((ext_vector_type(4))) __bf16 bf16x4;
typedef __attribute__((ext_vector_type(4))) float f32x4;
typedef __attribute__((ext_vector_type(16))) float f32x16;

__device__ __forceinline__ void gload_lds16(const void* g, void* l) {
  __builtin_amdgcn_global_load_lds(
      (const __attribute__((address_space(1))) void*)g,
      (__attribute__((address_space(3))) void*)l, 16, 0, 0);
}

#define MFMA16(a, b, c) __builtin_amdgcn_mfma_f32_16x16x32_bf16((a), (b), (c), 0, 0, 0)
#define MFMA32(a, b, c) __builtin_amdgcn_mfma_f32_32x32x16_bf16((a), (b), (c), 0, 0, 0)

__device__ __forceinline__ unsigned cvtpk_bf16(float lo, float hi) {
  unsigned r;
  asm("v_cvt_pk_bf16_f32 %0, %1, %2" : "=v"(r) : "v"(lo), "v"(hi));
  return r;
}

__device__ __forceinline__ float max3f(float a, float b, float c) {
  float d;
  asm("v_max3_f32 %0, %1, %2, %3" : "=v"(d) : "v"(a), "v"(b), "v"(c));
  return d;
}

// ---------------- fp32 -> bf16 conversion (8 arrays, grid.y selects) ----------------
struct ConvDesc {
  const float* s[8];
  __bf16* d[8];
  int n4[8];
};

__global__ __launch_bounds__(256) void convert_f32_bf16(ConvDesc cd) {
  const int a = blockIdx.y;
  const float* __restrict__ src = cd.s[a];
  __bf16* __restrict__ dst = cd.d[a];
  const int n4 = cd.n4[a];
  const int stride = gridDim.x * blockDim.x;
  for (int i = blockIdx.x * blockDim.x + threadIdx.x; i < n4; i += stride) {
    float4 v = ((const float4*)src)[i];
    bf16x4 o = {(__bf16)v.x, (__bf16)v.y, (__bf16)v.z, (__bf16)v.w};
    ((bf16x4*)dst)[i] = o;
  }
}

// ---------------- past_v [B,H,P,DH] f32  ->  Vt [B,H,DH,T] bf16 (cols 0..P) ----------------
__global__ __launch_bounds__(256) void transpose_pastv(const float* __restrict__ pv,
                                                       __bf16* __restrict__ vt) {
  __shared__ float tile[64][65];
  const int bh = blockIdx.y;
  const int k0 = blockIdx.x * 64;
  const int tx = threadIdx.x & 63, ty = threadIdx.x >> 6;
#pragma unroll
  for (int i = 0; i < 16; ++i) {
    const int r = ty + i * 4;
    tile[r][tx] = pv[((size_t)bh * PP + k0 + r) * DH + tx];
  }
  __syncthreads();
#pragma unroll
  for (int i = 0; i < 16; ++i) {
    const int d = ty + i * 4;
    vt[((size_t)bh * DH + d) * TT + k0 + tx] = (__bf16)tile[tx][d];
  }
}

// ---------------- shared 128x128x(K=1024) bf16 GEMM core (C = A * Bt^T) ----------------
__device__ __forceinline__ void gemm_core(const __bf16* A, const __bf16* Bt, __bf16* As,
                                          __bf16* Bs, int m0, int n0, f32x4 acc[4][4]) {
  const int tid = threadIdx.x, w = tid >> 6, lane = tid & 63;
  const int l15 = lane & 15, lg = lane >> 4;
  const int wr = w >> 1, wc = w & 1;
  const int cidx = w * 128 + lane;
  const int r0 = cidx >> 2, c0 = cidx & 3;   // row 0..127, 16B chunk 0..3
  const int r1 = r0 + 16;
  for (int kt = 0; kt < 32; ++kt) {
    const int k0 = kt * 32;
    if (kt) __syncthreads();
    gload_lds16(A + (size_t)(m0 + r0) * EE + k0 + c0 * 8, As + w * 1024);
    gload_lds16(A + (size_t)(m0 + r1) * EE + k0 + c0 * 8, As + w * 1024 + 512);
    gload_lds16(Bt + (size_t)(n0 + r0) * EE + k0 + c0 * 8, Bs + w * 1024);
    gload_lds16(Bt + (size_t)(n0 + r1) * EE + k0 + c0 * 8, Bs + w * 1024 + 512);
    __syncthreads();
    bf16x8 af[4], bf[4];
#pragma unroll
    for (int mi = 0; mi < 4; ++mi)
      af[mi] = *(const bf16x8*)&As[(wr * 64 + mi * 16 + l15) * 32 + lg * 8];
#pragma unroll
    for (int ni = 0; ni < 4; ++ni)
      bf[ni] = *(const bf16x8*)&Bs[(wc * 64 + ni * 16 + l15) * 32 + lg * 8];
#pragma unroll
    for (int mi = 0; mi < 4; ++mi)
#pragma unroll
      for (int ni = 0; ni < 4; ++ni) acc[mi][ni] = MFMA16(af[mi], bf[ni], acc[mi][ni]);
  }
}

// ---------------- QKV projections (z = 0:Q(scaled) 1:K 2:V(transposed into Vt)) ----------------
__global__ __launch_bounds__(256) void proj_qkv(
    const __bf16* __restrict__ xq, const __bf16* __restrict__ xk, const __bf16* __restrict__ xv,
    const __bf16* __restrict__ wqb, const __bf16* __restrict__ wkb, const __bf16* __restrict__ wvb,
    __bf16* __restrict__ qws, __bf16* __restrict__ kproj, __bf16* __restrict__ vt) {
  __shared__ alignas(16) __bf16 As[4096];
  __shared__ alignas(16) __bf16 Bs[4096];
  const int z = blockIdx.z;
  const __bf16* A = (z == 0) ? xq : (z == 1) ? xk : xv;
  const __bf16* Bt = (z == 0) ? wqb : (z == 1) ? wkb : wvb;
  const int m0 = blockIdx.y * 128, n0 = blockIdx.x * 128;
  f32x4 acc[4][4];
  const f32x4 fz = {0.f, 0.f, 0.f, 0.f};
#pragma unroll
  for (int mi = 0; mi < 4; ++mi)
#pragma unroll
    for (int ni = 0; ni < 4; ++ni) acc[mi][ni] = fz;
  gemm_core(A, Bt, As, Bs, m0, n0, acc);

  const int tid = threadIdx.x, w = tid >> 6, lane = tid & 63;
  const int l15 = lane & 15, lg = lane >> 4;
  const int wr = w >> 1, wc = w & 1;
  if (z < 2) {
    __bf16* dst = (z == 0) ? qws : kproj;
    const float sc = (z == 0) ? 0.125f : 1.0f;  // fold 1/sqrt(DH) into Q
#pragma unroll
    for (int mi = 0; mi < 4; ++mi)
#pragma unroll
      for (int ni = 0; ni < 4; ++ni) {
        const int mb = m0 + wr * 64 + mi * 16 + lg * 4;
        const int n = n0 + wc * 64 + ni * 16 + l15;
#pragma unroll
        for (int r = 0; r < 4; ++r)
          dst[(size_t)(mb + r) * EE + n] = (__bf16)(acc[mi][ni][r] * sc);
      }
  } else {
#pragma unroll
    for (int mi = 0; mi < 4; ++mi)
#pragma unroll
      for (int ni = 0; ni < 4; ++ni) {
        const int mb = m0 + wr * 64 + mi * 16 + lg * 4;
        const int n = n0 + wc * 64 + ni * 16 + l15;
        const int bb = mb >> 11, s = mb & (SS - 1);
        const int hh = n >> 6, dd = n & 63;
        bf16x4 pk = {(__bf16)acc[mi][ni][0], (__bf16)acc[mi][ni][1], (__bf16)acc[mi][ni][2],
                     (__bf16)acc[mi][ni][3]};
        *(bf16x4*)&vt[((size_t)(bb * HH + hh) * DH + dd) * TT + PP + s] = pk;
      }
  }
}

// ---------------- output projection: attn_out @ Wo^T -> fp32 d_out ----------------
__global__ __launch_bounds__(256) void gemm_out(const __bf16* __restrict__ A,
                                                const __bf16* __restrict__ Bt,
                                                float* __restrict__ C) {
  __shared__ alignas(16) __bf16 As[4096];
  __shared__ alignas(16) __bf16 Bs[4096];
  const int m0 = blockIdx.y * 128, n0 = blockIdx.x * 128;
  f32x4 acc[4][4];
  const f32x4 fz = {0.f, 0.f, 0.f, 0.f};
#pragma unroll
  for (int mi = 0; mi < 4; ++mi)
#pragma unroll
    for (int ni = 0; ni < 4; ++ni) acc[mi][ni] = fz;
  gemm_core(A, Bt, As, Bs, m0, n0, acc);

  const int tid = threadIdx.x, w = tid >> 6, lane = tid & 63;
  const int l15 = lane & 15, lg = lane >> 4;
  const int wr = w >> 1, wc = w & 1;
#pragma unroll
  for (int mi = 0; mi < 4; ++mi)
#pragma unroll
    for (int ni = 0; ni < 4; ++ni) {
      const int mb = m0 + wr * 64 + mi * 16 + lg * 4;
      const int n = n0 + wc * 64 + ni * 16 + l15;
#pragma unroll
      for (int r = 0; r < 4; ++r) C[(size_t)(mb + r) * EE + n] = acc[mi][ni][r];
    }
}

// ---------------- flash attention v3: split-T (2 balanced halves), 4 waves x 32 q ----------------
// Swapped QK^T (S^T = K*Q^T): softmax row lane-local. PV as O^T = V^T*P^T.
// Per-half normalized O (bf16) + (m,l) stats; combine kernel merges halves.
__global__ __launch_bounds__(256) void attn_kernel(const __bf16* __restrict__ q_ws,
                                                   const __bf16* __restrict__ kpast,
                                                   const __bf16* __restrict__ kproj,
                                                   const __bf16* __restrict__ vt,
                                                   __bf16* __restrict__ o0,
                                                   __bf16* __restrict__ o1,
                                                   float2* __restrict__ stats) {
  __shared__ alignas(16) __bf16 lds[2][2][4096];  // [buf][K/V][64x64], XOR-swizzled

  const int tid = threadIdx.x;
  const int w = tid >> 6, lane = tid & 63;
  const int l31 = lane & 31, hi = lane >> 5, l7 = lane & 7;

  const int qb = blockIdx.x;    // 0..15
  const int bh = blockIdx.y;    // 0..31
  const int half = blockIdx.z;  // 0..1
  const int b = bh >> 4, h = bh & 15;
  const int i0 = qb * 128;
  const int qw0 = i0 + w * 32;  // wave's first q row

  // balanced split: half0 = [0, 17+qb), half1 = [17+qb, 34+2qb) -- both 17+qb tiles
  const int tstart = half ? (17 + qb) : 0;
  const int tend = half ? (2 * qb + 34) : (17 + qb);

  // ---- Q B-frags: lane holds Q[q=qw0+l31][k=16c+hi*8+j], pre-scaled by 0.125 ----
  bf16x8 qf[4];
  {
    const __bf16* qbase = q_ws + (size_t)(b * SS + qw0 + l31) * EE + h * DH + hi * 8;
#pragma unroll
    for (int c = 0; c < 4; ++c) qf[c] = *(const bf16x8*)(qbase + 16 * c);
  }

  f32x16 oacc[2];
#pragma unroll
  for (int dblk = 0; dblk < 2; ++dblk)
#pragma unroll
    for (int r = 0; r < 16; ++r) oacc[dblk][r] = 0.f;
  float m_run = -1e30f, l_run = 0.f;

  // staging map: LDS[row][cl] holds global chunk cg = cl ^ (row&7)
  const int sr = (lane >> 3);
  const int scg = (lane & 7) ^ (sr & 7);

#define STAGE(buf, t)                                                                        \
  {                                                                                          \
    const int kv0_ = (t)*64;                                                                 \
    _Pragma("unroll") for (int i = 0; i < 2; ++i) {                                          \
      const int row_ = i * 32 + w * 8 + sr;                                                  \
      const __bf16* kg_ =                                                                    \
          ((t) < 32) ? kpast + ((size_t)bh * PP + kv0_ + row_) * DH + scg * 8                \
                     : kproj + ((size_t)(b * SS + kv0_ - PP + row_)) * EE + h * DH + scg * 8; \
      gload_lds16(kg_, &lds[buf][0][i * 2048 + w * 512]);                                    \
    }                                                                                        \
    _Pragma("unroll") for (int i = 0; i < 2; ++i) {                                          \
      const int row_ = i * 32 + w * 8 + sr;                                                  \
      gload_lds16(vt + ((size_t)bh * DH + row_) * TT + kv0_ + scg * 8,                       \
                  &lds[buf][1][i * 2048 + w * 512]);                                         \
    }                                                                                        \
  }

  STAGE(0, tstart);
  int cur = 0;

  for (int t = tstart; t < tend; ++t) {
    if (t + 1 < tend) {
      STAGE(cur ^ 1, t + 1);
      asm volatile("s_waitcnt vmcnt(4)" ::: "memory");  // tile t staged; t+1 in flight
    } else {
      asm volatile("s_waitcnt vmcnt(0)" ::: "memory");
    }
    __builtin_amdgcn_s_barrier();

    const int kv0 = t * 64;
    if (kv0 <= qw0 + 31 + PP) {  // wave-uniform visibility
      // ---- QK^T: S^T[key][q] ----
      f32x16 p[2];
#pragma unroll
      for (int s = 0; s < 2; ++s)
#pragma unroll
        for (int r = 0; r < 16; ++r) p[s][r] = 0.f;
      const __bf16* Kb = lds[cur][0];
#pragma unroll
      for (int s = 0; s < 2; ++s)
#pragma unroll
        for (int c = 0; c < 4; ++c) {
          const bf16x8 kf = *(const bf16x8*)&Kb[(32 * s + l31) * 64 + (((2 * c + hi) ^ l7) << 3)];
          p[s] = MFMA32(kf, qf[c], p[s]);
        }

      // ---- causal mask (boundary tiles only) ----
      if (kv0 + 63 > qw0 + PP) {
        const int qa = qw0 + l31 + PP;
#pragma unroll
        for (int s = 0; s < 2; ++s)
#pragma unroll
          for (int r = 0; r < 16; ++r) {
            const int key = kv0 + 32 * s + (r & 3) + 8 * (r >> 2) + 4 * hi;
            if (key > qa) p[s][r] = -1e30f;
          }
      }

      // ---- wave-local row max (max3 tree) ----
      float t8[8];
#pragma unroll
      for (int r = 0; r < 8; ++r) t8[r] = max3f(p[0][r], p[0][r + 8], p[1][r]);
#pragma unroll
      for (int r = 0; r < 8; ++r) t8[r] = fmaxf(t8[r], p[1][r + 8]);
      const float a3 = max3f(t8[0], t8[1], t8[2]);
      const float b3 = max3f(t8[3], t8[4], t8[5]);
      const float c3 = max3f(t8[6], t8[7], a3);
      float rmax = fmaxf(b3, c3);
      rmax = fmaxf(rmax, __shfl_xor(rmax, 32, 64));

      // ---- defer-max: rescale only when max grows materially ----
      if (!__all(rmax <= m_run + 8.0f)) {
        const float mnew = fmaxf(m_run, rmax);
        const float alpha = __builtin_amdgcn_exp2f((m_run - mnew) * 1.44269504f);
        l_run *= alpha;
#pragma unroll
        for (int dblk = 0; dblk < 2; ++dblk)
#pragma unroll
          for (int r = 0; r < 16; ++r) oacc[dblk][r] *= alpha;
        m_run = mnew;
      }
      const float mb = m_run * 1.44269504f;

#pragma unroll
      for (int s = 0; s < 2; ++s)
#pragma unroll
        for (int r = 0; r < 16; ++r)
          p[s][r] = __builtin_amdgcn_exp2f(__builtin_fmaf(p[s][r], 1.44269504f, -mb));
      float s16[16];
#pragma unroll
      for (int r = 0; r < 16; ++r) s16[r] = p[0][r] + p[1][r];
#pragma unroll
      for (int st = 8; st > 0; st >>= 1)
#pragma unroll
        for (int r = 0; r < st; ++r) s16[r] += s16[r + st];
      l_run += s16[0] + __shfl_xor(s16[0], 32, 64);

      // ---- P(f32) -> P^T B-frags (bf16) via cvt_pk + permlane32_swap ----
      bf16x8 pb[4];
#pragma unroll
      for (int s = 0; s < 2; ++s)
#pragma unroll
        for (int u = 0; u < 2; ++u) {
          unsigned a0 = cvtpk_bf16(p[s][8 * u + 0], p[s][8 * u + 1]);
          unsigned a1 = cvtpk_bf16(p[s][8 * u + 2], p[s][8 * u + 3]);
          unsigned b0 = cvtpk_bf16(p[s][8 * u + 4], p[s][8 * u + 5]);
          unsigned b1 = cvtpk_bf16(p[s][8 * u + 6], p[s][8 * u + 7]);
          asm volatile("v_permlane32_swap_b32 %0, %1" : "+v"(a0), "+v"(b0));
          asm volatile("v_permlane32_swap_b32 %0, %1" : "+v"(a1), "+v"(b1));
          union {
            unsigned u32[4];
            bf16x8 v;
          } pk;
          pk.u32[0] = a0;
          pk.u32[1] = a1;
          pk.u32[2] = b0;
          pk.u32[3] = b1;
          pb[2 * s + u] = pk.v;
        }

      // ---- PV: O^T += V^T * P^T ----
      const __bf16* Vb = lds[cur][1];
#pragma unroll
      for (int dblk = 0; dblk < 2; ++dblk)
#pragma unroll
        for (int u = 0; u < 4; ++u) {
          const bf16x8 vf =
              *(const bf16x8*)&Vb[(32 * dblk + l31) * 64 + (((2 * u + hi) ^ l7) << 3)];
          oacc[dblk] = MFMA32(vf, pb[u], oacc[dblk]);
        }
    }
    __builtin_amdgcn_s_barrier();
    cur ^= 1;
  }

  // ---- epilogue: per-half normalize + stats ----
  const float inv = 1.0f / l_run;
  __bf16* od = half ? o1 : o0;
  const size_t orow = (size_t)(b * SS + qw0 + l31) * EE + h * DH;
#pragma unroll
  for (int dblk = 0; dblk < 2; ++dblk)
#pragma unroll
    for (int g = 0; g < 4; ++g) {
      bf16x4 v4;
#pragma unroll
      for (int r4 = 0; r4 < 4; ++r4) v4[r4] = (__bf16)(oacc[dblk][4 * g + r4] * inv);
      *(bf16x4*)&od[orow + 32 * dblk + 8 * g + 4 * hi] = v4;
    }
  if (hi == 0) {
    stats[((size_t)half * BB * SS + b * SS + qw0 + l31) * HH + h] = float2{m_run, l_run};
  }
}

// ---------------- combine the two halves -> AO ----------------
__global__ __launch_bounds__(256) void combine_halves(const __bf16* __restrict__ o0,
                                                      const __bf16* __restrict__ o1,
                                                      const float2* __restrict__ st,
                                                      __bf16* __restrict__ ao) {
  const int tid = threadIdx.x;
  const int row = blockIdx.x * 2 + (tid >> 7);  // 0..4095
  const int c8 = tid & 127;                     // 8-col group
  const int h = c8 >> 3;
  const float2 s0 = st[(size_t)row * HH + h];
  const float2 s1 = st[(size_t)(BB * SS + row) * HH + h];
  const float m = fmaxf(s0.x, s1.x);
  float w0 = __builtin_amdgcn_exp2f((s0.x - m) * 1.44269504f) * s0.y;
  float w1 = __builtin_amdgcn_exp2f((s1.x - m) * 1.44269504f) * s1.y;
  const float inv = 1.0f / (w0 + w1);
  w0 *= inv;
  w1 *= inv;
  const size_t off = (size_t)row * EE + c8 * 8;
  const bf16x8 a = *(const bf16x8*)(o0 + off);
  const bf16x8 b = *(const bf16x8*)(o1 + off);
  bf16x8 o;
#pragma unroll
  for (int r = 0; r < 8; ++r) o[r] = (__bf16)(w0 * (float)a[r] + w1 * (float)b[r]);
  *(bf16x8*)(ao + off) = o;
}

// ---------------- launch ----------------
extern "C" void kernel_launch(void* const* d_in, const int* in_sizes, int n_in, void* d_out,
                              int out_size, void* d_ws, size_t ws_size, hipStream_t stream) {
  const float* query = (const float*)d_in[0];
  const float* key_in = (const float*)d_in[1];
  const float* value = (const float*)d_in[2];
  const float* past_k = (const float*)d_in[3];
  const float* past_v = (const float*)d_in[4];
  // d_in[5] = attn_mask: analytic causal, not loaded
  const float* Wq = (const float*)d_in[6];
  const float* Wk = (const float*)d_in[7];
  const float* Wv = (const float*)d_in[8];
  const float* Wo = (const float*)d_in[9];

  char* ws = (char*)d_ws;
  __bf16* XQ = (__bf16*)(ws + 0);                  // [4096,1024]; later: stats (1MB)
  __bf16* XK = (__bf16*)(ws + 8388608);            // later: AO (8MB)
  __bf16* XV = (__bf16*)(ws + 16777216);           // later: o1 (8MB)
  __bf16* WQB = (__bf16*)(ws + 25165824);          // [1024,1024] x4
  __bf16* WKB = (__bf16*)(ws + 27262976);
  __bf16* WVB = (__bf16*)(ws + 29360128);
  __bf16* WOB = (__bf16*)(ws + 31457280);
  __bf16* QW = (__bf16*)(ws + 33554432);           // Q, [B,S,E], pre-scaled
  __bf16* KP = (__bf16*)(ws + 41943040);           // past_k bf16 [B,H,P,DH]
  __bf16* KN = (__bf16*)(ws + 50331648);           // new K [B,S,E]
  __bf16* VT = (__bf16*)(ws + 58720256);           // V^T [B,H,DH,T]
  __bf16* O0 = (__bf16*)(ws + 75497472);           // half-0 O [B,S,E]
  __bf16* O1 = XV;                                 // half-1 O (reuses XV after proj)
  float2* ST = (float2*)(ws + 0);                  // stats [2][B*S][H] (reuses XQ after proj)
  __bf16* AO = XK;                                 // combined attn out (reuses XK after proj)

  ConvDesc cd;
  cd.s[0] = query;  cd.d[0] = XQ;  cd.n4[0] = 1048576;
  cd.s[1] = key_in; cd.d[1] = XK;  cd.n4[1] = 1048576;
  cd.s[2] = value;  cd.d[2] = XV;  cd.n4[2] = 1048576;
  cd.s[3] = Wq;     cd.d[3] = WQB; cd.n4[3] = 262144;
  cd.s[4] = Wk;     cd.d[4] = WKB; cd.n4[4] = 262144;
  cd.s[5] = Wv;     cd.d[5] = WVB; cd.n4[5] = 262144;
  cd.s[6] = Wo;     cd.d[6] = WOB; cd.n4[6] = 262144;
  cd.s[7] = past_k; cd.d[7] = KP;  cd.n4[7] = 1048576;

  convert_f32_bf16<<<dim3(1024, 8, 1), 256, 0, stream>>>(cd);
  transpose_pastv<<<dim3(32, 32, 1), 256, 0, stream>>>(past_v, VT);
  proj_qkv<<<dim3(8, 32, 3), 256, 0, stream>>>(XQ, XK, XV, WQB, WKB, WVB, QW, KN, VT);
  attn_kernel<<<dim3(16, 32, 2), 256, 0, stream>>>(QW, KP, KN, VT, O0, O1, ST);
  combine_halves<<<dim3(2048, 1, 1), 256, 0, stream>>>(O0, O1, ST, AO);
  gemm_out<<<dim3(8, 32, 1), 256, 0, stream>>>(AO, WOB, (float*)d_out);
}

// Round 4
// 204.569 us; speedup vs baseline: 1.3660x; 1.0134x over previous
//
#include <hip/hip_runtime.h>

#define BB 2
#define SS 2048
#define PP 2048
#define TT 4096
#define EE 1024
#define HH 16
#define DH 64

typedef __attribute__((ext_vector_type(8))) __bf16 bf16x8;
typedef __attribute__((ext_vector_type(4))) __bf16 bf16x4;
typedef __attribute__((ext_vector_type(4))) float f32x4;
typedef __attribute__((ext_vector_type(16))) float f32x16;

__device__ __forceinline__ void gload_lds16(const void* g, void* l) {
  __builtin_amdgcn_global_load_lds(
      (const __attribute__((address_space(1))) void*)g,
      (__attribute__((address_space(3))) void*)l, 16, 0, 0);
}

#define MFMA16(a, b, c) __builtin_amdgcn_mfma_f32_16x16x32_bf16((a), (b), (c), 0, 0, 0)
#define MFMA32(a, b, c) __builtin_amdgcn_mfma_f32_32x32x16_bf16((a), (b), (c), 0, 0, 0)

__device__ __forceinline__ unsigned cvtpk_bf16(float lo, float hi) {
  unsigned r;
  asm("v_cvt_pk_bf16_f32 %0, %1, %2" : "=v"(r) : "v"(lo), "v"(hi));
  return r;
}

__device__ __forceinline__ float max3f(float a, float b, float c) {
  float d;
  asm("v_max3_f32 %0, %1, %2, %3" : "=v"(d) : "v"(a), "v"(b), "v"(c));
  return d;
}

// ---------------- fp32 -> bf16 conversion (8 arrays, grid.y selects) ----------------
struct ConvDesc {
  const float* s[8];
  __bf16* d[8];
  int n4[8];
};

__global__ __launch_bounds__(256) void convert_f32_bf16(ConvDesc cd) {
  const int a = blockIdx.y;
  const float* __restrict__ src = cd.s[a];
  __bf16* __restrict__ dst = cd.d[a];
  const int n4 = cd.n4[a];
  const int stride = gridDim.x * blockDim.x;
  for (int i = blockIdx.x * blockDim.x + threadIdx.x; i < n4; i += stride) {
    float4 v = ((const float4*)src)[i];
    bf16x4 o = {(__bf16)v.x, (__bf16)v.y, (__bf16)v.z, (__bf16)v.w};
    ((bf16x4*)dst)[i] = o;
  }
}

// ---------------- past_v [B,H,P,DH] f32  ->  Vt [B,H,DH,T] bf16 (cols 0..P) ----------------
__global__ __launch_bounds__(256) void transpose_pastv(const float* __restrict__ pv,
                                                       __bf16* __restrict__ vt) {
  __shared__ float tile[64][65];
  const int bh = blockIdx.y;
  const int k0 = blockIdx.x * 64;
  const int tx = threadIdx.x & 63, ty = threadIdx.x >> 6;
#pragma unroll
  for (int i = 0; i < 16; ++i) {
    const int r = ty + i * 4;
    tile[r][tx] = pv[((size_t)bh * PP + k0 + r) * DH + tx];
  }
  __syncthreads();
#pragma unroll
  for (int i = 0; i < 16; ++i) {
    const int d = ty + i * 4;
    vt[((size_t)bh * DH + d) * TT + k0 + tx] = (__bf16)tile[tx][d];
  }
}

// ---------------- shared 128x128x(K=1024) bf16 GEMM core (C = A * Bt^T) ----------------
__device__ __forceinline__ void gemm_core(const __bf16* A, const __bf16* Bt, __bf16* As,
                                          __bf16* Bs, int m0, int n0, f32x4 acc[4][4]) {
  const int tid = threadIdx.x, w = tid >> 6, lane = tid & 63;
  const int l15 = lane & 15, lg = lane >> 4;
  const int wr = w >> 1, wc = w & 1;
  const int cidx = w * 128 + lane;
  const int r0 = cidx >> 2, c0 = cidx & 3;   // row 0..127, 16B chunk 0..3
  const int r1 = r0 + 16;
  for (int kt = 0; kt < 32; ++kt) {
    const int k0 = kt * 32;
    if (kt) __syncthreads();
    gload_lds16(A + (size_t)(m0 + r0) * EE + k0 + c0 * 8, As + w * 1024);
    gload_lds16(A + (size_t)(m0 + r1) * EE + k0 + c0 * 8, As + w * 1024 + 512);
    gload_lds16(Bt + (size_t)(n0 + r0) * EE + k0 + c0 * 8, Bs + w * 1024);
    gload_lds16(Bt + (size_t)(n0 + r1) * EE + k0 + c0 * 8, Bs + w * 1024 + 512);
    __syncthreads();
    bf16x8 af[4], bf[4];
#pragma unroll
    for (int mi = 0; mi < 4; ++mi)
      af[mi] = *(const bf16x8*)&As[(wr * 64 + mi * 16 + l15) * 32 + lg * 8];
#pragma unroll
    for (int ni = 0; ni < 4; ++ni)
      bf[ni] = *(const bf16x8*)&Bs[(wc * 64 + ni * 16 + l15) * 32 + lg * 8];
#pragma unroll
    for (int mi = 0; mi < 4; ++mi)
#pragma unroll
      for (int ni = 0; ni < 4; ++ni) acc[mi][ni] = MFMA16(af[mi], bf[ni], acc[mi][ni]);
  }
}

// ---------------- QKV projections (z = 0:Q(scaled) 1:K 2:V(transposed into Vt)) ----------------
__global__ __launch_bounds__(256) void proj_qkv(
    const __bf16* __restrict__ xq, const __bf16* __restrict__ xk, const __bf16* __restrict__ xv,
    const __bf16* __restrict__ wqb, const __bf16* __restrict__ wkb, const __bf16* __restrict__ wvb,
    __bf16* __restrict__ qws, __bf16* __restrict__ kproj, __bf16* __restrict__ vt) {
  __shared__ alignas(16) __bf16 As[4096];
  __shared__ alignas(16) __bf16 Bs[4096];
  const int z = blockIdx.z;
  const __bf16* A = (z == 0) ? xq : (z == 1) ? xk : xv;
  const __bf16* Bt = (z == 0) ? wqb : (z == 1) ? wkb : wvb;
  const int m0 = blockIdx.y * 128, n0 = blockIdx.x * 128;
  f32x4 acc[4][4];
  const f32x4 fz = {0.f, 0.f, 0.f, 0.f};
#pragma unroll
  for (int mi = 0; mi < 4; ++mi)
#pragma unroll
    for (int ni = 0; ni < 4; ++ni) acc[mi][ni] = fz;
  gemm_core(A, Bt, As, Bs, m0, n0, acc);

  const int tid = threadIdx.x, w = tid >> 6, lane = tid & 63;
  const int l15 = lane & 15, lg = lane >> 4;
  const int wr = w >> 1, wc = w & 1;
  if (z < 2) {
    __bf16* dst = (z == 0) ? qws : kproj;
    // Q scale = 1/sqrt(DH) * log2(e): softmax runs in base-2 domain
    const float sc = (z == 0) ? 0.180336884f : 1.0f;
#pragma unroll
    for (int mi = 0; mi < 4; ++mi)
#pragma unroll
      for (int ni = 0; ni < 4; ++ni) {
        const int mb = m0 + wr * 64 + mi * 16 + lg * 4;
        const int n = n0 + wc * 64 + ni * 16 + l15;
#pragma unroll
        for (int r = 0; r < 4; ++r)
          dst[(size_t)(mb + r) * EE + n] = (__bf16)(acc[mi][ni][r] * sc);
      }
  } else {
#pragma unroll
    for (int mi = 0; mi < 4; ++mi)
#pragma unroll
      for (int ni = 0; ni < 4; ++ni) {
        const int mb = m0 + wr * 64 + mi * 16 + lg * 4;
        const int n = n0 + wc * 64 + ni * 16 + l15;
        const int bb = mb >> 11, s = mb & (SS - 1);
        const int hh = n >> 6, dd = n & 63;
        bf16x4 pk = {(__bf16)acc[mi][ni][0], (__bf16)acc[mi][ni][1], (__bf16)acc[mi][ni][2],
                     (__bf16)acc[mi][ni][3]};
        *(bf16x4*)&vt[((size_t)(bb * HH + hh) * DH + dd) * TT + PP + s] = pk;
      }
  }
}

// ---------------- output projection: attn_out @ Wo^T -> fp32 d_out ----------------
__global__ __launch_bounds__(256) void gemm_out(const __bf16* __restrict__ A,
                                                const __bf16* __restrict__ Bt,
                                                float* __restrict__ C) {
  __shared__ alignas(16) __bf16 As[4096];
  __shared__ alignas(16) __bf16 Bs[4096];
  const int m0 = blockIdx.y * 128, n0 = blockIdx.x * 128;
  f32x4 acc[4][4];
  const f32x4 fz = {0.f, 0.f, 0.f, 0.f};
#pragma unroll
  for (int mi = 0; mi < 4; ++mi)
#pragma unroll
    for (int ni = 0; ni < 4; ++ni) acc[mi][ni] = fz;
  gemm_core(A, Bt, As, Bs, m0, n0, acc);

  const int tid = threadIdx.x, w = tid >> 6, lane = tid & 63;
  const int l15 = lane & 15, lg = lane >> 4;
  const int wr = w >> 1, wc = w & 1;
#pragma unroll
  for (int mi = 0; mi < 4; ++mi)
#pragma unroll
    for (int ni = 0; ni < 4; ++ni) {
      const int mb = m0 + wr * 64 + mi * 16 + lg * 4;
      const int n = n0 + wc * 64 + ni * 16 + l15;
#pragma unroll
      for (int r = 0; r < 4; ++r) C[(size_t)(mb + r) * EE + n] = acc[mi][ni][r];
    }
}

// ---------------- flash attention v4: split-T halves, single barrier/tile, log2 domain ----------------
__global__ __launch_bounds__(256) void attn_kernel(const __bf16* __restrict__ q_ws,
                                                   const __bf16* __restrict__ kpast,
                                                   const __bf16* __restrict__ kproj,
                                                   const __bf16* __restrict__ vt,
                                                   __bf16* __restrict__ o0,
                                                   __bf16* __restrict__ o1,
                                                   float2* __restrict__ stats) {
  __shared__ alignas(16) __bf16 lds[2][2][4096];  // [buf][K/V][64x64], XOR-swizzled

  const int tid = threadIdx.x;
  const int w = tid >> 6, lane = tid & 63;
  const int l31 = lane & 31, hi = lane >> 5, l7 = lane & 7;

  const int qb = blockIdx.x;    // 0..15
  const int bh = blockIdx.y;    // 0..31
  const int half = blockIdx.z;  // 0..1
  const int b = bh >> 4, h = bh & 15;
  const int i0 = qb * 128;
  const int qw0 = i0 + w * 32;  // wave's first q row

  // balanced split: half0 = [0, 17+qb), half1 = [17+qb, 34+2qb) -- both 17+qb tiles
  const int tstart = half ? (17 + qb) : 0;
  const int tend = half ? (2 * qb + 34) : (17 + qb);

  // ---- Q B-frags (pre-scaled by 0.125*log2e at projection) ----
  bf16x8 qf[4];
  {
    const __bf16* qbase = q_ws + (size_t)(b * SS + qw0 + l31) * EE + h * DH + hi * 8;
#pragma unroll
    for (int c = 0; c < 4; ++c) qf[c] = *(const bf16x8*)(qbase + 16 * c);
  }

  f32x16 oacc[2];
#pragma unroll
  for (int dblk = 0; dblk < 2; ++dblk)
#pragma unroll
    for (int r = 0; r < 16; ++r) oacc[dblk][r] = 0.f;
  float m_run = -1e30f, l_run = 0.f;  // m_run in log2 units

  // staging map: LDS[row][cl] holds global chunk cg = cl ^ (row&7)
  const int sr = (lane >> 3);
  const int scg = (lane & 7) ^ (sr & 7);

#define STAGE(buf, t)                                                                        \
  {                                                                                          \
    const int kv0_ = (t)*64;                                                                 \
    _Pragma("unroll") for (int i = 0; i < 2; ++i) {                                          \
      const int row_ = i * 32 + w * 8 + sr;                                                  \
      const __bf16* kg_ =                                                                    \
          ((t) < 32) ? kpast + ((size_t)bh * PP + kv0_ + row_) * DH + scg * 8                \
                     : kproj + ((size_t)(b * SS + kv0_ - PP + row_)) * EE + h * DH + scg * 8; \
      gload_lds16(kg_, &lds[buf][0][i * 2048 + w * 512]);                                    \
    }                                                                                        \
    _Pragma("unroll") for (int i = 0; i < 2; ++i) {                                          \
      const int row_ = i * 32 + w * 8 + sr;                                                  \
      gload_lds16(vt + ((size_t)bh * DH + row_) * TT + kv0_ + scg * 8,                       \
                  &lds[buf][1][i * 2048 + w * 512]);                                         \
    }                                                                                        \
  }

  STAGE(0, tstart);
  int cur = 0;

  for (int t = tstart; t < tend; ++t) {
    // single barrier per tile: separates compute(t-1) (all waves) from restaging its buffer
    __builtin_amdgcn_s_barrier();
    if (t + 1 < tend) {
      STAGE(cur ^ 1, t + 1);
      asm volatile("s_waitcnt vmcnt(4)" ::: "memory");  // tile t ready; t+1 stays in flight
    } else {
      asm volatile("s_waitcnt vmcnt(0)" ::: "memory");
    }

    const int kv0 = t * 64;
    if (kv0 <= qw0 + 31 + PP) {  // wave-uniform visibility
      // ---- QK^T: S^T[key][q] (scores already in log2 domain) ----
      f32x16 p[2];
#pragma unroll
      for (int s = 0; s < 2; ++s)
#pragma unroll
        for (int r = 0; r < 16; ++r) p[s][r] = 0.f;
      const __bf16* Kb = lds[cur][0];
      __builtin_amdgcn_s_setprio(1);
#pragma unroll
      for (int s = 0; s < 2; ++s)
#pragma unroll
        for (int c = 0; c < 4; ++c) {
          const bf16x8 kf = *(const bf16x8*)&Kb[(32 * s + l31) * 64 + (((2 * c + hi) ^ l7) << 3)];
          p[s] = MFMA32(kf, qf[c], p[s]);
        }
      __builtin_amdgcn_s_setprio(0);

      // ---- causal mask (boundary tiles only) ----
      if (kv0 + 63 > qw0 + PP) {
        const int qa = qw0 + l31 + PP;
#pragma unroll
        for (int s = 0; s < 2; ++s)
#pragma unroll
          for (int r = 0; r < 16; ++r) {
            const int key = kv0 + 32 * s + (r & 3) + 8 * (r >> 2) + 4 * hi;
            if (key > qa) p[s][r] = -1e30f;
          }
      }

      // ---- wave-local row max (max3 tree) ----
      float t8[8];
#pragma unroll
      for (int r = 0; r < 8; ++r) t8[r] = max3f(p[0][r], p[0][r + 8], p[1][r]);
#pragma unroll
      for (int r = 0; r < 8; ++r) t8[r] = fmaxf(t8[r], p[1][r + 8]);
      const float a3 = max3f(t8[0], t8[1], t8[2]);
      const float b3 = max3f(t8[3], t8[4], t8[5]);
      const float c3 = max3f(t8[6], t8[7], a3);
      float rmax = fmaxf(b3, c3);
      rmax = fmaxf(rmax, __shfl_xor(rmax, 32, 64));

      // ---- defer-max: rescale only when max grows materially (log2 units, bound 2^8) ----
      if (!__all(rmax <= m_run + 8.0f)) {
        const float mnew = fmaxf(m_run, rmax);
        const float alpha = __builtin_amdgcn_exp2f(m_run - mnew);
        l_run *= alpha;
#pragma unroll
        for (int dblk = 0; dblk < 2; ++dblk)
#pragma unroll
          for (int r = 0; r < 16; ++r) oacc[dblk][r] *= alpha;
        m_run = mnew;
      }

#pragma unroll
      for (int s = 0; s < 2; ++s)
#pragma unroll
        for (int r = 0; r < 16; ++r) p[s][r] = __builtin_amdgcn_exp2f(p[s][r] - m_run);
      float s16[16];
#pragma unroll
      for (int r = 0; r < 16; ++r) s16[r] = p[0][r] + p[1][r];
#pragma unroll
      for (int st = 8; st > 0; st >>= 1)
#pragma unroll
        for (int r = 0; r < st; ++r) s16[r] += s16[r + st];
      l_run += s16[0] + __shfl_xor(s16[0], 32, 64);

      // ---- P(f32) -> P^T B-frags (bf16) via cvt_pk + permlane32_swap ----
      bf16x8 pb[4];
#pragma unroll
      for (int s = 0; s < 2; ++s)
#pragma unroll
        for (int u = 0; u < 2; ++u) {
          unsigned a0 = cvtpk_bf16(p[s][8 * u + 0], p[s][8 * u + 1]);
          unsigned a1 = cvtpk_bf16(p[s][8 * u + 2], p[s][8 * u + 3]);
          unsigned b0 = cvtpk_bf16(p[s][8 * u + 4], p[s][8 * u + 5]);
          unsigned b1 = cvtpk_bf16(p[s][8 * u + 6], p[s][8 * u + 7]);
          asm volatile("v_permlane32_swap_b32 %0, %1" : "+v"(a0), "+v"(b0));
          asm volatile("v_permlane32_swap_b32 %0, %1" : "+v"(a1), "+v"(b1));
          union {
            unsigned u32[4];
            bf16x8 v;
          } pk;
          pk.u32[0] = a0;
          pk.u32[1] = a1;
          pk.u32[2] = b0;
          pk.u32[3] = b1;
          pb[2 * s + u] = pk.v;
        }

      // ---- PV: O^T += V^T * P^T ----
      const __bf16* Vb = lds[cur][1];
      __builtin_amdgcn_s_setprio(1);
#pragma unroll
      for (int dblk = 0; dblk < 2; ++dblk)
#pragma unroll
        for (int u = 0; u < 4; ++u) {
          const bf16x8 vf =
              *(const bf16x8*)&Vb[(32 * dblk + l31) * 64 + (((2 * u + hi) ^ l7) << 3)];
          oacc[dblk] = MFMA32(vf, pb[u], oacc[dblk]);
        }
      __builtin_amdgcn_s_setprio(0);
    }
    cur ^= 1;
  }

  // ---- epilogue: per-half normalize + stats (m in log2 units) ----
  const float inv = 1.0f / l_run;
  __bf16* od = half ? o1 : o0;
  const size_t orow = (size_t)(b * SS + qw0 + l31) * EE + h * DH;
#pragma unroll
  for (int dblk = 0; dblk < 2; ++dblk)
#pragma unroll
    for (int g = 0; g < 4; ++g) {
      bf16x4 v4;
#pragma unroll
      for (int r4 = 0; r4 < 4; ++r4) v4[r4] = (__bf16)(oacc[dblk][4 * g + r4] * inv);
      *(bf16x4*)&od[orow + 32 * dblk + 8 * g + 4 * hi] = v4;
    }
  if (hi == 0) {
    stats[((size_t)half * BB * SS + b * SS + qw0 + l31) * HH + h] = float2{m_run, l_run};
  }
}

// ---------------- combine the two halves -> AO (stats m in log2 units) ----------------
__global__ __launch_bounds__(256) void combine_halves(const __bf16* __restrict__ o0,
                                                      const __bf16* __restrict__ o1,
                                                      const float2* __restrict__ st,
                                                      __bf16* __restrict__ ao) {
  const int tid = threadIdx.x;
  const int row = blockIdx.x * 2 + (tid >> 7);  // 0..4095
  const int c8 = tid & 127;                     // 8-col group
  const int h = c8 >> 3;
  const float2 s0 = st[(size_t)row * HH + h];
  const float2 s1 = st[(size_t)(BB * SS + row) * HH + h];
  const float m = fmaxf(s0.x, s1.x);
  float w0 = __builtin_amdgcn_exp2f(s0.x - m) * s0.y;
  float w1 = __builtin_amdgcn_exp2f(s1.x - m) * s1.y;
  const float inv = 1.0f / (w0 + w1);
  w0 *= inv;
  w1 *= inv;
  const size_t off = (size_t)row * EE + c8 * 8;
  const bf16x8 a = *(const bf16x8*)(o0 + off);
  const bf16x8 b = *(const bf16x8*)(o1 + off);
  bf16x8 o;
#pragma unroll
  for (int r = 0; r < 8; ++r) o[r] = (__bf16)(w0 * (float)a[r] + w1 * (float)b[r]);
  *(bf16x8*)(ao + off) = o;
}

// ---------------- launch ----------------
extern "C" void kernel_launch(void* const* d_in, const int* in_sizes, int n_in, void* d_out,
                              int out_size, void* d_ws, size_t ws_size, hipStream_t stream) {
  const float* query = (const float*)d_in[0];
  const float* key_in = (const float*)d_in[1];
  const float* value = (const float*)d_in[2];
  const float* past_k = (const float*)d_in[3];
  const float* past_v = (const float*)d_in[4];
  // d_in[5] = attn_mask: analytic causal, not loaded
  const float* Wq = (const float*)d_in[6];
  const float* Wk = (const float*)d_in[7];
  const float* Wv = (const float*)d_in[8];
  const float* Wo = (const float*)d_in[9];

  char* ws = (char*)d_ws;
  __bf16* XQ = (__bf16*)(ws + 0);                  // [4096,1024]; later: stats (1MB)
  __bf16* XK = (__bf16*)(ws + 8388608);            // later: AO (8MB)
  __bf16* XV = (__bf16*)(ws + 16777216);           // later: o1 (8MB)
  __bf16* WQB = (__bf16*)(ws + 25165824);          // [1024,1024] x4
  __bf16* WKB = (__bf16*)(ws + 27262976);
  __bf16* WVB = (__bf16*)(ws + 29360128);
  __bf16* WOB = (__bf16*)(ws + 31457280);
  __bf16* QW = (__bf16*)(ws + 33554432);           // Q, [B,S,E], pre-scaled
  __bf16* KP = (__bf16*)(ws + 41943040);           // past_k bf16 [B,H,P,DH]
  __bf16* KN = (__bf16*)(ws + 50331648);           // new K [B,S,E]
  __bf16* VT = (__bf16*)(ws + 58720256);           // V^T [B,H,DH,T]
  __bf16* O0 = (__bf16*)(ws + 75497472);           // half-0 O [B,S,E]
  __bf16* O1 = XV;                                 // half-1 O (reuses XV after proj)
  float2* ST = (float2*)(ws + 0);                  // stats [2][B*S][H] (reuses XQ after proj)
  __bf16* AO = XK;                                 // combined attn out (reuses XK after proj)

  ConvDesc cd;
  cd.s[0] = query;  cd.d[0] = XQ;  cd.n4[0] = 1048576;
  cd.s[1] = key_in; cd.d[1] = XK;  cd.n4[1] = 1048576;
  cd.s[2] = value;  cd.d[2] = XV;  cd.n4[2] = 1048576;
  cd.s[3] = Wq;     cd.d[3] = WQB; cd.n4[3] = 262144;
  cd.s[4] = Wk;     cd.d[4] = WKB; cd.n4[4] = 262144;
  cd.s[5] = Wv;     cd.d[5] = WVB; cd.n4[5] = 262144;
  cd.s[6] = Wo;     cd.d[6] = WOB; cd.n4[6] = 262144;
  cd.s[7] = past_k; cd.d[7] = KP;  cd.n4[7] = 1048576;

  convert_f32_bf16<<<dim3(1024, 8, 1), 256, 0, stream>>>(cd);
  transpose_pastv<<<dim3(32, 32, 1), 256, 0, stream>>>(past_v, VT);
  proj_qkv<<<dim3(8, 32, 3), 256, 0, stream>>>(XQ, XK, XV, WQB, WKB, WVB, QW, KN, VT);
  attn_kernel<<<dim3(16, 32, 2), 256, 0, stream>>>(QW, KP, KN, VT, O0, O1, ST);
  combine_halves<<<dim3(2048, 1, 1), 256, 0, stream>>>(O0, O1, ST, AO);
  gemm_out<<<dim3(8, 32, 1), 256, 0, stream>>>(AO, WOB, (float*)d_out);
}